// Round 1
// baseline (585.350 us; speedup 1.0000x reference)
//
#include <hip/hip_runtime.h>

// B=256, T=2048, F=64, U=10 LSTM (Keras gate order i,f,g,o; softsign cell act)
#define B_ 256
#define T_ 2048
#define F_ 64
#define U_ 10
#define G_ 40  // 4*U

__device__ __forceinline__ float rcp_f(float x) { return __builtin_amdgcn_rcpf(x); }
__device__ __forceinline__ float sigm_f(float x) { return rcp_f(1.f + __expf(-x)); }
__device__ __forceinline__ float rdlane_f(float v, int l) {
  return __int_as_float(__builtin_amdgcn_readlane(__float_as_int(v), l));
}

// ---- Kernel A: permute W and bias into gate-interleaved layout ----
// Wp[f][u*4+gate] = W[f][gate*10+u]; bp[u*4+gate] = bias[gate*10+u]
__global__ void permute_w(const float* __restrict__ W, const float* __restrict__ bias,
                          float* __restrict__ Wp, float* __restrict__ bp) {
  int i = blockIdx.x * 256 + threadIdx.x;
  if (i < F_ * G_) {
    int f = i / G_, g = i % G_;
    int gate = g / U_, u = g % U_;
    Wp[f * G_ + u * 4 + gate] = W[i];
  }
  if (i < G_) {
    int gate = i / U_, u = i % U_;
    bp[u * 4 + gate] = bias[i];
  }
}

// ---- Kernel B: xzp[row][u*4+gate] = bias + sum_f x[grow][f]*W[f][g] ----
// 128 rows/block, 128 threads, thread = one row, 40 accumulators in VGPRs.
// W reads are wave-uniform (scalarizable to s_load); x staged via LDS coalesced.
__global__ __launch_bounds__(128) void input_gemm(
    const float* __restrict__ x, const float* __restrict__ Wp,
    const float* __restrict__ bp, float* __restrict__ xzp,
    int tcs, int c0) {
  __shared__ float4 xl4[16 * 129];  // [kc][row], pad row-dim 128->129
  const int tid = threadIdx.x;
  const long Tc_mask = (1L << tcs) - 1;
  const long row0 = (long)blockIdx.x * 128;
  // stage: 128 rows x 16 float4 — fully coalesced global reads
  #pragma unroll
  for (int j = 0; j < 16; ++j) {
    int flat = j * 128 + tid;      // float4 index within block's rows
    int r = flat >> 4, kc = flat & 15;
    long rl = row0 + r;
    long b = rl >> tcs;
    long tl = rl & Tc_mask;
    long grow = b * T_ + c0 + tl;  // global (b,t) row
    xl4[kc * 129 + r] = ((const float4*)x)[grow * 16 + kc];
  }
  __syncthreads();
  const float4* W4 = (const float4*)Wp;
  float4 acc[10];
  #pragma unroll
  for (int q = 0; q < 10; ++q) acc[q] = ((const float4*)bp)[q];
  for (int k = 0; k < 16; ++k) {
    float4 xv = xl4[k * 129 + tid];
    #pragma unroll
    for (int c = 0; c < 4; ++c) {
      float xf = (c == 0) ? xv.x : (c == 1) ? xv.y : (c == 2) ? xv.z : xv.w;
      #pragma unroll
      for (int q = 0; q < 10; ++q) {
        float4 w = W4[(4 * k + c) * 10 + q];  // wave-uniform -> s_load
        acc[q].x = fmaf(xf, w.x, acc[q].x);
        acc[q].y = fmaf(xf, w.y, acc[q].y);
        acc[q].z = fmaf(xf, w.z, acc[q].z);
        acc[q].w = fmaf(xf, w.w, acc[q].w);
      }
    }
  }
  float4* o4 = (float4*)(xzp + (row0 + tid) * G_);
  #pragma unroll
  for (int q = 0; q < 10; ++q) o4[q] = acc[q];
}

// ---- Kernel C: LSTM recurrence over one chunk of Tc timesteps ----
// One wave per batch element; lane u owns unit u (lanes>=10 mirror lane 9).
// h broadcast via v_readlane; even/odd split halves the fma dependency chain.
__global__ __launch_bounds__(64) void lstm_scan(
    const float* __restrict__ xzp, const float* __restrict__ R,
    const float* __restrict__ dw, const float* __restrict__ db,
    float* __restrict__ out, float* __restrict__ hs, float* __restrict__ cs,
    int Tc, int first, int last) {
  const int b = blockIdx.x;
  const int lane = threadIdx.x;
  const int u = (lane < U_) ? lane : (U_ - 1);
  float Ri[10], Rf[10], Rg[10], Ro[10];
  #pragma unroll
  for (int j = 0; j < 10; ++j) {
    Ri[j] = R[j * G_ + u];
    Rf[j] = R[j * G_ + 10 + u];
    Rg[j] = R[j * G_ + 20 + u];
    Ro[j] = R[j * G_ + 30 + u];
  }
  float h, c;
  if (first) { h = 0.f; c = 0.f; }
  else       { h = hs[b * U_ + u]; c = cs[b * U_ + u]; }
  const float4* zp = (const float4*)xzp + (long)b * Tc * U_ + u;
  float4 buf[4];
  #pragma unroll
  for (int k = 0; k < 4; ++k) buf[k] = zp[k * U_];
  zp += 4 * U_;
  for (int t0 = 0; t0 < Tc; t0 += 4) {
    #pragma unroll
    for (int k = 0; k < 4; ++k) {
      float4 z4 = buf[k];
      buf[k] = zp[k * U_];  // prefetch t0+4+k; tail overreads into Wp region (in ws, unused)
      float zi0 = z4.x, zf0 = z4.y, zg0 = z4.z, zo0 = z4.w;
      float zi1 = 0.f, zf1 = 0.f, zg1 = 0.f, zo1 = 0.f;
      #pragma unroll
      for (int j = 0; j < 10; j += 2) {
        float ha = rdlane_f(h, j);
        float hb = rdlane_f(h, j + 1);
        zi0 = fmaf(ha, Ri[j], zi0);  zi1 = fmaf(hb, Ri[j + 1], zi1);
        zf0 = fmaf(ha, Rf[j], zf0);  zf1 = fmaf(hb, Rf[j + 1], zf1);
        zg0 = fmaf(ha, Rg[j], zg0);  zg1 = fmaf(hb, Rg[j + 1], zg1);
        zo0 = fmaf(ha, Ro[j], zo0);  zo1 = fmaf(hb, Ro[j + 1], zo1);
      }
      float ig = sigm_f(zi0 + zi1);
      float fg = sigm_f(zf0 + zf1);
      float zg = zg0 + zg1;
      float gg = zg * rcp_f(1.f + __builtin_fabsf(zg));  // softsign
      float og = sigm_f(zo0 + zo1);
      c = fmaf(fg, c, ig * gg);
      h = og * c * rcp_f(1.f + __builtin_fabsf(c));      // o * softsign(c)
    }
    zp += 4 * U_;
  }
  if (last) {
    float p = h * dw[u];
    float logit = db[0];
    #pragma unroll
    for (int j = 0; j < 10; ++j) logit += rdlane_f(p, j);
    if (lane == 0) out[b] = sigm_f(logit);
  } else if (lane < U_) {
    hs[b * U_ + lane] = h;
    cs[b * U_ + lane] = c;
  }
}

extern "C" void kernel_launch(void* const* d_in, const int* in_sizes, int n_in,
                              void* d_out, int out_size, void* d_ws, size_t ws_size,
                              hipStream_t stream) {
  const float* x    = (const float*)d_in[0];  // [256,2048,64]
  const float* W    = (const float*)d_in[1];  // [64,40]
  const float* R    = (const float*)d_in[2];  // [10,40]
  const float* bias = (const float*)d_in[3];  // [40]
  const float* dw   = (const float*)d_in[4];  // [10,1]
  const float* db   = (const float*)d_in[5];  // [1]
  float* out = (float*)d_out;                 // [256]

  // Chunk T so xz scratch fits in ws (Tc=2048 in one shot if ws >= ~84 MB).
  const size_t fixed = (size_t)(2560 + 40 + 2560 + 2560) * sizeof(float);
  int Tc = T_;
  while (Tc > 16 && (size_t)B_ * Tc * G_ * sizeof(float) + fixed + 1024 > ws_size) Tc >>= 1;
  int tcs = 31 - __builtin_clz((unsigned)Tc);

  float* xzp = (float*)d_ws;                       // [256][Tc][10][4]
  float* Wp  = xzp + (size_t)B_ * Tc * G_;         // 2560 floats (also prefetch overread pad)
  float* bp  = Wp + 2560;                          // 40 floats
  float* hs  = bp + 40;                            // 2560 floats
  float* cs  = hs + 2560;                          // 2560 floats

  permute_w<<<10, 256, 0, stream>>>(W, bias, Wp, bp);
  int nchunk = T_ / Tc;
  for (int ci = 0; ci < nchunk; ++ci) {
    input_gemm<<<2 * Tc, 128, 0, stream>>>(x, Wp, bp, xzp, tcs, ci * Tc);
    lstm_scan<<<B_, 64, 0, stream>>>(xzp, R, dw, db, out, hs, cs,
                                     Tc, ci == 0 ? 1 : 0, ci == nchunk - 1 ? 1 : 0);
  }
}

// Round 2
// 481.849 us; speedup vs baseline: 1.2148x; 1.2148x over previous
//
#include <hip/hip_runtime.h>

// B=256, T=2048, F=64, U=10 LSTM (Keras gate order i,f,g,o; softsign cell act)
#define B_ 256
#define T_ 2048
#define F_ 64
#define U_ 10
#define G_ 40  // 4*U

__device__ __forceinline__ float rcp_f(float x) { return __builtin_amdgcn_rcpf(x); }
__device__ __forceinline__ float sigm_f(float x) { return rcp_f(1.f + __expf(-x)); }
__device__ __forceinline__ float rdlane_f(float v, int l) {
  return __int_as_float(__builtin_amdgcn_readlane(__float_as_int(v), l));
}
__device__ __forceinline__ float bperm_f(int srclane, float v) {
  return __int_as_float(__builtin_amdgcn_ds_bpermute(srclane * 4, __float_as_int(v)));
}

// ---- Kernel A: xz[row][g] = bias[g] + sum_f x[grow][f]*W[f][g]  (natural layout)
// 256 threads = 256 rows/block. x staged via LDS in 16-feature chunks; W read as
// wave-uniform global float4 (10 in flight); 40 fp32 accumulators in VGPRs.
// __launch_bounds__(256,2): allow ~256 VGPRs so nothing spills.
__global__ __launch_bounds__(256, 2) void input_gemm(
    const float* __restrict__ x, const float* __restrict__ W,
    const float* __restrict__ bias, float* __restrict__ xz,
    int tcs, int c0) {
  __shared__ float4 xl4[4 * 257];  // [kc][row], pad 256->257
  const int tid = threadIdx.x;
  const long Tc_mask = (1L << tcs) - 1;
  const long row0 = (long)blockIdx.x * 256;
  const float4* W4 = (const float4*)W;  // W4[k*10+q] = cols 4q..4q+3 of feature k

  float4 acc[10];
  #pragma unroll
  for (int q = 0; q < 10; ++q) acc[q] = ((const float4*)bias)[q];

  for (int kc = 0; kc < 4; ++kc) {  // 16 features per chunk
    // stage: 256 rows x 4 float4 — 64B-granule coalesced
    __syncthreads();
    #pragma unroll
    for (int i = 0; i < 4; ++i) {
      int j = i * 256 + tid;
      int r = j >> 2, kl = j & 3;
      long rl = row0 + r;
      long b = rl >> tcs;
      long grow = b * T_ + c0 + (rl & Tc_mask);
      xl4[kl * 257 + r] = ((const float4*)x)[grow * 16 + kc * 4 + kl];
    }
    __syncthreads();
    #pragma unroll
    for (int kl = 0; kl < 4; ++kl) {
      float4 xv = xl4[kl * 257 + tid];
      #pragma unroll
      for (int c = 0; c < 4; ++c) {
        float xf = (c == 0) ? xv.x : (c == 1) ? xv.y : (c == 2) ? xv.z : xv.w;
        int k = kc * 16 + kl * 4 + c;
        #pragma unroll
        for (int q = 0; q < 10; ++q) {
          float4 w = W4[k * 10 + q];  // wave-uniform address
          acc[q].x = fmaf(xf, w.x, acc[q].x);
          acc[q].y = fmaf(xf, w.y, acc[q].y);
          acc[q].z = fmaf(xf, w.z, acc[q].z);
          acc[q].w = fmaf(xf, w.w, acc[q].w);
        }
      }
    }
  }
  float4* o4 = (float4*)(xz + (row0 + tid) * G_);
  #pragma unroll
  for (int q = 0; q < 10; ++q) o4[q] = acc[q];
}

// ---- Kernel B: LSTM recurrence. One wave per batch element.
// Lane L<40 owns (gate=L/10, unit=L%10): 10 fma/step instead of 40.
// z loads are lane-contiguous dwords, register-prefetched 16 steps deep
// (~2000 cyc slack >> 900 cyc HBM latency). Gate gather via 4x ds_bpermute;
// c,h computed redundantly in all lanes of a unit; h broadcast via readlane.
__global__ __launch_bounds__(64) void lstm_scan(
    const float* __restrict__ xz, const float* __restrict__ R,
    const float* __restrict__ dw, const float* __restrict__ db,
    float* __restrict__ out, float* __restrict__ hs, float* __restrict__ cs,
    int Tc, int first, int last) {
  const int b = blockIdx.x;
  const int lane = threadIdx.x;
  const int L = (lane < G_) ? lane : (G_ - 1);
  const int u = L % U_;
  const int gate = L / U_;
  float Rc[10];
  #pragma unroll
  for (int j = 0; j < 10; ++j) Rc[j] = R[j * G_ + L];
  float h, c;
  if (first) { h = 0.f; c = 0.f; }
  else       { h = hs[b * U_ + u]; c = cs[b * U_ + u]; }
  const float* zr = xz + (long)b * Tc * G_ + L;
  float zbuf[16];
  #pragma unroll
  for (int k = 0; k < 16; ++k) zbuf[k] = zr[k * G_];
  zr += 16 * G_;
  for (int t0 = 0; t0 < Tc; t0 += 16) {
    #pragma unroll
    for (int k = 0; k < 16; ++k) {
      float z0 = zbuf[k];
      zbuf[k] = zr[k * G_];  // prefetch t0+16+k (tail overreads into pad region)
      float z1 = 0.f;
      #pragma unroll
      for (int j = 0; j < 10; j += 2) {
        float ha = rdlane_f(h, j);
        float hb = rdlane_f(h, j + 1);
        z0 = fmaf(ha, Rc[j], z0);
        z1 = fmaf(hb, Rc[j + 1], z1);
      }
      float z = z0 + z1;
      float sg = sigm_f(z);
      float ss = z * rcp_f(1.f + __builtin_fabsf(z));
      float a = (gate == 2) ? ss : sg;  // cndmask, no divergence
      float ai = bperm_f(u, a);
      float af = bperm_f(u + 10, a);
      float ag = bperm_f(u + 20, a);
      float ao = bperm_f(u + 30, a);
      c = fmaf(af, c, ai * ag);
      h = ao * c * rcp_f(1.f + __builtin_fabsf(c));  // o * softsign(c)
    }
    zr += 16 * G_;
  }
  if (last) {
    float p = h * dw[u];
    float logit = db[0];
    #pragma unroll
    for (int j = 0; j < 10; ++j) logit += rdlane_f(p, j);
    if (lane == 0) out[b] = sigm_f(logit);
  } else if (lane < U_) {
    hs[b * U_ + lane] = h;
    cs[b * U_ + lane] = c;
  }
}

extern "C" void kernel_launch(void* const* d_in, const int* in_sizes, int n_in,
                              void* d_out, int out_size, void* d_ws, size_t ws_size,
                              hipStream_t stream) {
  const float* x    = (const float*)d_in[0];  // [256,2048,64]
  const float* W    = (const float*)d_in[1];  // [64,40]
  const float* R    = (const float*)d_in[2];  // [10,40]
  const float* bias = (const float*)d_in[3];  // [40]
  const float* dw   = (const float*)d_in[4];  // [10,1]
  const float* db   = (const float*)d_in[5];  // [1]
  float* out = (float*)d_out;                 // [256]

  // Chunk T so xz scratch fits in ws (Tc=2048 in one shot if ws >= ~84 MB).
  const size_t fixed = (size_t)(2560 /*prefetch pad*/ + 2560 + 2560) * sizeof(float);
  int Tc = T_;
  while (Tc > 16 && (size_t)B_ * Tc * G_ * sizeof(float) + fixed + 1024 > ws_size) Tc >>= 1;
  int tcs = 31 - __builtin_clz((unsigned)Tc);

  float* xz = (float*)d_ws;                   // [256][Tc][40] natural layout
  float* hs = xz + (size_t)B_ * Tc * G_ + 2560;  // +2560 floats prefetch-overread pad
  float* cs = hs + 2560;

  int nchunk = T_ / Tc;
  for (int ci = 0; ci < nchunk; ++ci) {
    input_gemm<<<Tc, 256, 0, stream>>>(x, W, bias, xz, tcs, ci * Tc);
    lstm_scan<<<B_, 64, 0, stream>>>(xz, R, dw, db, out, hs, cs,
                                     Tc, ci == 0 ? 1 : 0, ci == nchunk - 1 ? 1 : 0);
  }
}

// Round 3
// 455.590 us; speedup vs baseline: 1.2848x; 1.0576x over previous
//
#include <hip/hip_runtime.h>

// B=256, T=2048, F=64, U=10 LSTM (Keras gates i,f,g,o; softsign cell act).
// Fully fused single kernel: block = batch element. Wave0 = sequential scan
// (lane L=u*4+gate owns matrix column gate*10+u; gate gather via DPP quad
// broadcasts). Waves 1-3 = producers computing z = x@W + bias one 64-step
// chunk ahead into double-buffered LDS; x chunks DMA'd 2 ahead via
// global_load_lds (16 KB contiguous). One barrier per chunk.
#define B_ 256
#define T_ 2048
#define F_ 64
#define U_ 10
#define G_ 40
#define CH 64          // timesteps per chunk
#define NCH (T_ / CH)  // 32

__device__ __forceinline__ float rcp_f(float x) { return __builtin_amdgcn_rcpf(x); }
__device__ __forceinline__ float rdlane_f(float v, int l) {
  return __int_as_float(__builtin_amdgcn_readlane(__float_as_int(v), l));
}
template <int CTRL>
__device__ __forceinline__ float qbcast(float v) {  // quad_perm broadcast
  return __int_as_float(
      __builtin_amdgcn_update_dpp(0, __float_as_int(v), CTRL, 0xF, 0xF, true));
}
__device__ __forceinline__ void gload_lds16(const float* g, float* l) {
  // lane i lands at l + i*16B; g is per-lane address (contiguous across wave)
  __builtin_amdgcn_global_load_lds(
      (const __attribute__((address_space(1))) void*)g,
      (__attribute__((address_space(3))) void*)l, 16, 0, 0);
}

__global__ __launch_bounds__(256) void lstm_fused(
    const float* __restrict__ x, const float* __restrict__ W,
    const float* __restrict__ R, const float* __restrict__ bias,
    const float* __restrict__ dw, const float* __restrict__ db,
    float* __restrict__ out) {
  __shared__ float xb[2][CH * F_];  // 2 x 16 KB x-chunk buffers
  __shared__ float zb[2][CH * G_];  // 2 x 10 KB z-chunk buffers
  const int b = blockIdx.x;
  const int tid = threadIdx.x;
  const int wave = tid >> 6;
  const int lane = tid & 63;
  const float* xbase = x + (size_t)b * T_ * F_;

  if (wave == 0) {
    // ---------------- scan wave ----------------
    const int L = (lane < G_) ? lane : (G_ - 1);
    const int u = L >> 2, gate = L & 3;
    const int col = gate * U_ + u;
    float Rc[U_];
    #pragma unroll
    for (int j = 0; j < U_; ++j) Rc[j] = R[j * G_ + col];
    const float dwu = dw[u];
    const float db0 = db[0];
    float h = 0.f, c = 0.f;
    __syncthreads();  // #1: x(0),x(1) DMA complete
    __syncthreads();  // #2: z(0) produced
    for (int cc = 0; cc < NCH; ++cc) {
      const float* zrow = zb[cc & 1];
      float z0p = zrow[0 * G_ + L];
      float z1p = zrow[1 * G_ + L];
      for (int tt = 0; tt < CH; ++tt) {
        float z0 = z0p;
        z0p = z1p;
        int tn = (tt + 2 < CH) ? tt + 2 : CH - 1;  // 2-ahead LDS prefetch
        z1p = zrow[tn * G_ + L];
        float z1 = 0.f;
        #pragma unroll
        for (int j = 0; j < U_; j += 2) {  // even/odd split: 5-deep chains
          float ha = rdlane_f(h, 4 * j);
          float hb = rdlane_f(h, 4 * (j + 1));
          z0 = fmaf(ha, Rc[j], z0);
          z1 = fmaf(hb, Rc[j + 1], z1);
        }
        float zz = z0 + z1;
        float sg = rcp_f(1.f + __expf(-zz));                  // sigmoid
        float ss = zz * rcp_f(1.f + __builtin_fabsf(zz));     // softsign
        float a = (gate == 2) ? ss : sg;                      // cndmask
        float ai = qbcast<0x00>(a);  // quad lane0 = gate i
        float af = qbcast<0x55>(a);  // lane1 = f
        float ag = qbcast<0xAA>(a);  // lane2 = g
        float ao = qbcast<0xFF>(a);  // lane3 = o
        c = fmaf(af, c, ai * ag);
        h = ao * c * rcp_f(1.f + __builtin_fabsf(c));         // o*softsign(c)
      }
      __syncthreads();  // chunk boundary
    }
    // epilogue: logit = sum_u h[u]*dw[u] + db; out = sigmoid(logit)
    float p = h * dwu;
    float logit = db0;
    #pragma unroll
    for (int j = 0; j < U_; ++j) logit += rdlane_f(p, 4 * j);
    if (lane == 0) out[b] = rcp_f(1.f + __expf(-logit));
  } else {
    // ---------------- producer waves (1..3) ----------------
    const int p = tid - 64;        // 0..191
    const int s = p % G_;          // column slot 0..39
    const int tsl = p / G_;        // t-slot 0..4 (active < 4)
    const bool act = (p < 160);
    const int u = s >> 2, gate = s & 3;
    const int col = gate * U_ + u;
    const int pw = wave - 1;       // 0..2
    float wcol[F_];
    #pragma unroll
    for (int k = 0; k < F_; ++k) wcol[k] = W[k * G_ + col];
    const float bcol = bias[col];

    auto load_x = [&](int cx) {  // DMA x chunk cx -> xb[cx&1]
      const float* g = xbase + (size_t)cx * CH * F_;
      float* l = xb[cx & 1];
      for (int i = pw; i < 16; i += 3)
        gload_lds16(g + (i * 64 + lane) * 4, l + i * 256);
    };
    auto produce = [&](int tc) {  // z chunk tc: xb[tc&1] -> zb[tc&1]
      const float* xr = xb[tc & 1];
      float* zrow = zb[tc & 1];
      for (int tt = tsl; tt < CH; tt += 4) {
        const float4* row4 = (const float4*)(xr + tt * F_);
        float z = bcol;
        #pragma unroll
        for (int j = 0; j < 16; ++j) {
          int k4 = (j + tsl * 4) & 15;  // rotate start: breaks LDS bank alias
          float4 xv = row4[k4];
          z = fmaf(xv.x, wcol[4 * k4 + 0], z);
          z = fmaf(xv.y, wcol[4 * k4 + 1], z);
          z = fmaf(xv.z, wcol[4 * k4 + 2], z);
          z = fmaf(xv.w, wcol[4 * k4 + 3], z);
        }
        zrow[tt * G_ + s] = z;
      }
    };

    load_x(0);
    load_x(1);
    __syncthreads();  // #1: x(0),x(1) visible (barrier drains vmcnt)
    if (act) produce(0);
    __syncthreads();  // #2: z(0) visible
    for (int cc = 0; cc < NCH; ++cc) {
      if (cc + 2 < NCH) load_x(cc + 2);
      if (cc + 1 < NCH && act) produce(cc + 1);
      __syncthreads();  // chunk boundary
    }
  }
}

extern "C" void kernel_launch(void* const* d_in, const int* in_sizes, int n_in,
                              void* d_out, int out_size, void* d_ws, size_t ws_size,
                              hipStream_t stream) {
  const float* x    = (const float*)d_in[0];  // [256,2048,64]
  const float* W    = (const float*)d_in[1];  // [64,40]
  const float* R    = (const float*)d_in[2];  // [10,40]
  const float* bias = (const float*)d_in[3];  // [40]
  const float* dw   = (const float*)d_in[4];  // [10,1]
  const float* db   = (const float*)d_in[5];  // [1]
  float* out = (float*)d_out;                 // [256]
  (void)d_ws; (void)ws_size;
  lstm_fused<<<B_, 256, 0, stream>>>(x, W, R, bias, dw, db, out);
}

// Round 4
// 408.162 us; speedup vs baseline: 1.4341x; 1.1162x over previous
//
#include <hip/hip_runtime.h>

// B=256, T=2048, F=64, U=10 LSTM (Keras gates i,f,g,o; softsign cell act).
// One block per batch element. Wave0 = sequential scan (lane L=u*4+gate;
// gate gather via DPP quad broadcasts). Waves 1-3 = producers: z = x@W+bias
// one 64-step chunk ahead into double-buffered LDS. x read straight from
// global (40 col-lanes share one row address -> broadcast coalesce), double-
// buffered in registers. NO dynamic VGPR-array indexing anywhere (R3's
// wcol[runtime] spilled to scratch: 12 MB WRITE_SIZE, 3x slowdown).
#define B_ 256
#define T_ 2048
#define F_ 64
#define U_ 10
#define G_ 40
#define CH 64          // timesteps per chunk
#define NCH (T_ / CH)  // 32

__device__ __forceinline__ float rcp_f(float x) { return __builtin_amdgcn_rcpf(x); }
__device__ __forceinline__ float rdlane_f(float v, int l) {
  return __int_as_float(__builtin_amdgcn_readlane(__float_as_int(v), l));
}
template <int CTRL>
__device__ __forceinline__ float qbcast(float v) {  // quad_perm broadcast
  return __int_as_float(
      __builtin_amdgcn_update_dpp(0, __float_as_int(v), CTRL, 0xF, 0xF, true));
}

__global__ __launch_bounds__(256, 1) void lstm_fused(
    const float* __restrict__ x, const float* __restrict__ W,
    const float* __restrict__ R, const float* __restrict__ bias,
    const float* __restrict__ dw, const float* __restrict__ db,
    float* __restrict__ out) {
  __shared__ float zb[2][CH * G_];  // double-buffered z chunks (2 x 10 KB)
  const int b = blockIdx.x;
  const int tid = threadIdx.x;
  const int wave = tid >> 6;
  const int lane = tid & 63;
  const float* xbase = x + (size_t)b * T_ * F_;

  if (wave == 0) {
    // ---------------- scan wave ----------------
    const int L = (lane < G_) ? lane : (G_ - 1);
    const int u = L >> 2, gate = L & 3;
    const int col = gate * U_ + u;
    float Rc[U_];
    #pragma unroll
    for (int j = 0; j < U_; ++j) Rc[j] = R[j * G_ + col];
    const float dwu = dw[u];
    const float db0 = db[0];
    float h = 0.f, c = 0.f;
    __syncthreads();  // B0: z(0) produced
    for (int cc = 0; cc < NCH; ++cc) {
      const float* zrow = zb[cc & 1] + L;
      float zpf[4];
      #pragma unroll
      for (int k = 0; k < 4; ++k) zpf[k] = zrow[k * G_];
      for (int t0 = 0; t0 < CH; t0 += 4) {
        #pragma unroll
        for (int k = 0; k < 4; ++k) {
          float z0 = zpf[k];
          int tn = t0 + 4 + k;               // 4-ahead LDS prefetch
          if (tn > CH - 1) tn = CH - 1;      // clamp (stale value unused)
          zpf[k] = zrow[tn * G_];
          float z1 = 0.f;
          #pragma unroll
          for (int j = 0; j < U_; j += 2) {  // even/odd: 5-deep fma chains
            float ha = rdlane_f(h, 4 * j);
            float hb = rdlane_f(h, 4 * (j + 1));
            z0 = fmaf(ha, Rc[j], z0);
            z1 = fmaf(hb, Rc[j + 1], z1);
          }
          float zz = z0 + z1;
          float sg = rcp_f(1.f + __expf(-zz));               // sigmoid
          float ss = zz * rcp_f(1.f + __builtin_fabsf(zz));  // softsign
          float a = (gate == 2) ? ss : sg;                   // cndmask
          float ai = qbcast<0x00>(a);
          float af = qbcast<0x55>(a);
          float ag = qbcast<0xAA>(a);
          float ao = qbcast<0xFF>(a);
          c = fmaf(af, c, ai * ag);
          h = ao * c * rcp_f(1.f + __builtin_fabsf(c));      // o*softsign(c)
        }
      }
      __syncthreads();  // B(cc+1)
    }
    // epilogue: logit = sum_u h[u]*dw[u] + db; out = sigmoid(logit)
    float p = h * dwu;
    float logit = db0;
    #pragma unroll
    for (int j = 0; j < U_; ++j) logit += rdlane_f(p, 4 * j);
    if (lane == 0) out[b] = rcp_f(1.f + __expf(-logit));
  } else {
    // ---------------- producer waves (1..3) ----------------
    const int p0 = tid - 64;                 // 0..191
    const int p = (p0 < 160) ? p0 : 159;
    const bool act = (p0 < 160);
    const int s = p % G_;                    // column slot 0..39
    const int tsl = p / G_;                  // t-slot 0..3
    const int u = s >> 2, gate = s & 3;
    const int col = gate * U_ + u;
    float wc[F_];
    #pragma unroll
    for (int k = 0; k < F_; ++k) wc[k] = W[k * G_ + col];
    const float bcol = bias[col];

    auto dot64 = [&](const float4* rb) {
      float z0 = bcol, z1 = 0.f, z2 = 0.f, z3 = 0.f;
      #pragma unroll
      for (int j = 0; j < 16; j += 4) {      // compile-time indices only!
        float4 a0 = rb[j], a1 = rb[j + 1], a2 = rb[j + 2], a3 = rb[j + 3];
        z0 = fmaf(a0.x, wc[4*j+0], z0);  z0 = fmaf(a0.y, wc[4*j+1], z0);
        z0 = fmaf(a0.z, wc[4*j+2], z0);  z0 = fmaf(a0.w, wc[4*j+3], z0);
        z1 = fmaf(a1.x, wc[4*j+4], z1);  z1 = fmaf(a1.y, wc[4*j+5], z1);
        z1 = fmaf(a1.z, wc[4*j+6], z1);  z1 = fmaf(a1.w, wc[4*j+7], z1);
        z2 = fmaf(a2.x, wc[4*j+8], z2);  z2 = fmaf(a2.y, wc[4*j+9], z2);
        z2 = fmaf(a2.z, wc[4*j+10], z2); z2 = fmaf(a2.w, wc[4*j+11], z2);
        z3 = fmaf(a3.x, wc[4*j+12], z3); z3 = fmaf(a3.y, wc[4*j+13], z3);
        z3 = fmaf(a3.z, wc[4*j+14], z3); z3 = fmaf(a3.w, wc[4*j+15], z3);
      }
      return (z0 + z1) + (z2 + z3);
    };

    auto produce = [&](int cc) {  // z chunk cc -> zb[cc&1]
      const float4* xr = (const float4*)(xbase + (size_t)cc * CH * F_);
      float* zrow = zb[cc & 1];
      float4 A[16], Bv[16];
      #pragma unroll
      for (int j = 0; j < 16; ++j) A[j] = xr[tsl * 16 + j];   // it=0 row
      for (int it = 0; it < 16; it += 2) {                    // 16 t per lane
        const int t0 = tsl + 4 * it;
        const int t1 = t0 + 4;
        #pragma unroll
        for (int j = 0; j < 16; ++j) Bv[j] = xr[t1 * 16 + j]; // prefetch it+1
        float za = dot64(A);
        if (act) zrow[t0 * G_ + s] = za;
        const int t2 = (it + 2 < 16) ? t0 + 8 : t0;           // guard tail
        #pragma unroll
        for (int j = 0; j < 16; ++j) A[j] = xr[t2 * 16 + j];  // prefetch it+2
        float zbv = dot64(Bv);
        if (act) zrow[t1 * G_ + s] = zbv;
      }
    };

    produce(0);
    __syncthreads();  // B0
    for (int cc = 0; cc < NCH; ++cc) {
      if (cc + 1 < NCH) produce(cc + 1);
      __syncthreads();  // B(cc+1)
    }
  }
}

extern "C" void kernel_launch(void* const* d_in, const int* in_sizes, int n_in,
                              void* d_out, int out_size, void* d_ws, size_t ws_size,
                              hipStream_t stream) {
  const float* x    = (const float*)d_in[0];  // [256,2048,64]
  const float* W    = (const float*)d_in[1];  // [64,40]
  const float* R    = (const float*)d_in[2];  // [10,40]
  const float* bias = (const float*)d_in[3];  // [40]
  const float* dw   = (const float*)d_in[4];  // [10,1]
  const float* db   = (const float*)d_in[5];  // [1]
  float* out = (float*)d_out;                 // [256]
  (void)d_ws; (void)ws_size; (void)in_sizes; (void)n_in; (void)out_size;
  lstm_fused<<<B_, 256, 0, stream>>>(x, W, R, bias, dw, db, out);
}

// Round 5
// 354.142 us; speedup vs baseline: 1.6529x; 1.1525x over previous
//
#include <hip/hip_runtime.h>

// B=256, T=2048, F=64, U=10 LSTM (Keras gates i,f,g,o; softsign cell act).
// One block per batch element. Wave0 = sequential scan (lane L=u*4+gate;
// gate gather via DPP quad broadcasts). Waves 1-3 = producers: z = x@W+bias
// one 64-step chunk ahead into double-buffered LDS z; x chunks DMA'd 2 ahead
// via global_load_lds (zero VGPR footprint -- R4's register double-buffer
// exceeded the compiler's VGPR cap and serialized on vmcnt). Producers read
// x rows from LDS (uniform-address broadcast, conflict-free). All register
// array indices compile-time (R3's dynamic wcol[] index spilled to scratch).
#define B_ 256
#define T_ 2048
#define F_ 64
#define U_ 10
#define G_ 40
#define CH 64          // timesteps per chunk
#define NCH (T_ / CH)  // 32

__device__ __forceinline__ float rcp_f(float x) { return __builtin_amdgcn_rcpf(x); }
__device__ __forceinline__ float rdlane_f(float v, int l) {
  return __int_as_float(__builtin_amdgcn_readlane(__float_as_int(v), l));
}
template <int CTRL>
__device__ __forceinline__ float qbcast(float v) {  // quad_perm broadcast
  return __int_as_float(
      __builtin_amdgcn_update_dpp(0, __float_as_int(v), CTRL, 0xF, 0xF, true));
}
__device__ __forceinline__ void gload_lds16(const float* g, float* l) {
  // lane i's 16B lands at l + i*16; g is per-lane (contiguous across wave)
  __builtin_amdgcn_global_load_lds(
      (const __attribute__((address_space(1))) void*)g,
      (__attribute__((address_space(3))) void*)l, 16, 0, 0);
}

__global__ __launch_bounds__(256, 1) void lstm_fused(
    const float* __restrict__ x, const float* __restrict__ W,
    const float* __restrict__ R, const float* __restrict__ bias,
    const float* __restrict__ dw, const float* __restrict__ db,
    float* __restrict__ out) {
  __shared__ float xb[2][CH * F_];  // 2 x 16 KB x-chunk buffers (DMA target)
  __shared__ float zb[2][CH * G_];  // 2 x 10 KB z-chunk buffers
  const int b = blockIdx.x;
  const int tid = threadIdx.x;
  const int wave = tid >> 6;
  const int lane = tid & 63;
  const float* xbase = x + (size_t)b * T_ * F_;

  if (wave == 0) {
    // ---------------- scan wave ----------------
    __builtin_amdgcn_s_setprio(3);
    const int L = (lane < G_) ? lane : (G_ - 1);
    const int u = L >> 2, gate = L & 3;
    const int col = gate * U_ + u;
    float Rc[U_];
    #pragma unroll
    for (int j = 0; j < U_; ++j) Rc[j] = R[j * G_ + col];
    const float dwu = dw[u];
    const float db0 = db[0];
    float h = 0.f, c = 0.f;
    __syncthreads();  // B-pre1: x(0),x(1) DMA complete
    __syncthreads();  // B-pre2: z(0) produced
    for (int cc = 0; cc < NCH; ++cc) {
      const float* zrow = zb[cc & 1] + L;
      float zpf[4];
      #pragma unroll
      for (int k = 0; k < 4; ++k) zpf[k] = zrow[k * G_];
      for (int t0 = 0; t0 < CH; t0 += 4) {
        #pragma unroll
        for (int k = 0; k < 4; ++k) {
          float z0 = zpf[k];
          int tn = t0 + 4 + k;               // 4-ahead LDS prefetch
          if (tn > CH - 1) tn = CH - 1;      // clamp (stale value unused)
          zpf[k] = zrow[tn * G_];
          float z1 = 0.f;
          #pragma unroll
          for (int j = 0; j < U_; j += 2) {  // even/odd: 5-deep fma chains
            float ha = rdlane_f(h, 4 * j);
            float hb = rdlane_f(h, 4 * (j + 1));
            z0 = fmaf(ha, Rc[j], z0);
            z1 = fmaf(hb, Rc[j + 1], z1);
          }
          float zz = z0 + z1;
          float sg = rcp_f(1.f + __expf(-zz));               // sigmoid
          float ss = zz * rcp_f(1.f + __builtin_fabsf(zz));  // softsign
          float a = (gate == 2) ? ss : sg;                   // cndmask
          float ai = qbcast<0x00>(a);
          float af = qbcast<0x55>(a);
          float ag = qbcast<0xAA>(a);
          float ao = qbcast<0xFF>(a);
          c = fmaf(af, c, ai * ag);
          float oc = ao * c;                                 // parallel with den
          float den = 1.f + __builtin_fabsf(c);
          h = oc * rcp_f(den);                               // o*softsign(c)
        }
      }
      __syncthreads();  // B(cc)
    }
    // epilogue: logit = sum_u h[u]*dw[u] + db; out = sigmoid(logit)
    float p = h * dwu;
    float logit = db0;
    #pragma unroll
    for (int j = 0; j < U_; ++j) logit += rdlane_f(p, 4 * j);
    if (lane == 0) out[b] = rcp_f(1.f + __expf(-logit));
  } else {
    // ---------------- producer waves (1..3) ----------------
    const int p0 = tid - 64;                 // 0..191
    const int p = (p0 < 160) ? p0 : 159;
    const bool act = (p0 < 160);
    const int s = p % G_;                    // column slot 0..39
    const int tsl = p / G_;                  // t-slot 0..3
    const int u = s >> 2, gate = s & 3;
    const int col = gate * U_ + u;
    const int pw = wave - 1;                 // 0..2
    float wc[F_];
    #pragma unroll
    for (int k = 0; k < F_; ++k) wc[k] = W[k * G_ + col];
    const float bcol = bias[col];

    auto load_x = [&](int cx) {  // DMA x chunk cx -> xb[cx&1] (16 KB, 16 instr)
      const float* g = xbase + (size_t)cx * CH * F_;
      float* l = xb[cx & 1];
      for (int i = pw; i < 16; i += 3)
        gload_lds16(g + i * 256 + lane * 4, l + i * 256);
    };
    auto produce = [&](int tc) {  // z chunk tc: xb[tc&1] -> zb[tc&1]
      const float* xr = xb[tc & 1];
      float* zrow = zb[tc & 1];
      for (int tt = tsl; tt < CH; tt += 4) {  // 16 t per lane
        const float4* row4 = (const float4*)(xr + tt * F_);
        float z0 = bcol, z1 = 0.f, z2 = 0.f, z3 = 0.f;
        #pragma unroll
        for (int j = 0; j < 16; j += 4) {     // compile-time indices only!
          float4 a0 = row4[j], a1 = row4[j + 1], a2 = row4[j + 2], a3 = row4[j + 3];
          z0 = fmaf(a0.x, wc[4*j+0], z0);  z0 = fmaf(a0.y, wc[4*j+1], z0);
          z0 = fmaf(a0.z, wc[4*j+2], z0);  z0 = fmaf(a0.w, wc[4*j+3], z0);
          z1 = fmaf(a1.x, wc[4*j+4], z1);  z1 = fmaf(a1.y, wc[4*j+5], z1);
          z1 = fmaf(a1.z, wc[4*j+6], z1);  z1 = fmaf(a1.w, wc[4*j+7], z1);
          z2 = fmaf(a2.x, wc[4*j+8], z2);  z2 = fmaf(a2.y, wc[4*j+9], z2);
          z2 = fmaf(a2.z, wc[4*j+10], z2); z2 = fmaf(a2.w, wc[4*j+11], z2);
          z3 = fmaf(a3.x, wc[4*j+12], z3); z3 = fmaf(a3.y, wc[4*j+13], z3);
          z3 = fmaf(a3.z, wc[4*j+14], z3); z3 = fmaf(a3.w, wc[4*j+15], z3);
        }
        if (act) zrow[tt * G_ + s] = (z0 + z1) + (z2 + z3);
      }
    };

    load_x(0);
    load_x(1);
    __syncthreads();  // B-pre1 (barrier drains vmcnt -> DMA visible)
    produce(0);
    __syncthreads();  // B-pre2
    for (int cc = 0; cc < NCH; ++cc) {
      if (cc + 2 < NCH) load_x(cc + 2);
      if (cc + 1 < NCH) produce(cc + 1);
      __syncthreads();  // B(cc)
    }
  }
}

extern "C" void kernel_launch(void* const* d_in, const int* in_sizes, int n_in,
                              void* d_out, int out_size, void* d_ws, size_t ws_size,
                              hipStream_t stream) {
  const float* x    = (const float*)d_in[0];  // [256,2048,64]
  const float* W    = (const float*)d_in[1];  // [64,40]
  const float* R    = (const float*)d_in[2];  // [10,40]
  const float* bias = (const float*)d_in[3];  // [40]
  const float* dw   = (const float*)d_in[4];  // [10,1]
  const float* db   = (const float*)d_in[5];  // [1]
  float* out = (float*)d_out;                 // [256]
  (void)d_ws; (void)ws_size; (void)in_sizes; (void)n_in; (void)out_size;
  lstm_fused<<<B_, 256, 0, stream>>>(x, W, R, bias, dw, db, out);
}